// Round 5
// baseline (304.601 us; speedup 1.0000x reference)
//
#include <hip/hip_runtime.h>
#include <cstdint>
#include <cstddef>

#define Bn 8192
#define Dn 1024
#define Hn 1024
#define En 8
#define MT 128                     // expert padding quantum / m-tile
#define PERM_N (Bn + En * MT)      // 9216
#define MTILES (PERM_N / MT)       // 72
#define NB 16                      // 64-col partial chunks per row
#define NBLK (8 * MTILES)          // 576 blocks total

// prep unit ranges (units distributed over blocks 1..575)
#define NXB 4096                   // x-convert units
#define NWB 2048                   // W1-transpose units
#define NUNITS (NXB + NWB)         // 6144

typedef unsigned short u16;
typedef __bf16 bf16x8 __attribute__((ext_vector_type(8)));
typedef float f32x4 __attribute__((ext_vector_type(4)));
typedef unsigned short ushort8 __attribute__((ext_vector_type(8)));

// ---------- helpers ----------
__device__ __forceinline__ u16 f2bf(float f) {
  unsigned int u = __float_as_uint(f);
  unsigned int r = u + 0x7fffu + ((u >> 16) & 1u);   // RNE
  return (u16)(r >> 16);
}

__device__ __forceinline__ void gld16(const void* g, void* l) {
  __builtin_amdgcn_global_load_lds(
      (const __attribute__((address_space(1))) void*)g,
      (__attribute__((address_space(3))) void*)l, 16, 0, 0);
}

// wait for own vmcnt<=N (lgkm/exp untouched), then workgroup barrier.
// imm: vmcnt[3:0] | expcnt[6:4] | lgkmcnt[11:8]
#define PIPE_BARRIER_VM4() do {                    \
    asm volatile("" ::: "memory");                 \
    __builtin_amdgcn_s_waitcnt(0x0F74);            \
    __builtin_amdgcn_s_barrier();                  \
    asm volatile("" ::: "memory");                 \
  } while (0)
#define PIPE_BARRIER_VM0() do {                    \
    asm volatile("" ::: "memory");                 \
    __builtin_amdgcn_s_waitcnt(0x0F70);            \
    __builtin_amdgcn_s_barrier();                  \
    asm volatile("" ::: "memory");                 \
  } while (0)

// ---------- fused kernel: prep -> grid barrier -> gemm -> ticketed probs ----
__global__ __launch_bounds__(256, 3) void fused_k(
    const float* __restrict__ x, const int* __restrict__ sidx,
    const float* __restrict__ W1, const float* __restrict__ b1,
    const float* __restrict__ w2, const float* __restrict__ b2,
    u16* __restrict__ xb, u16* __restrict__ w1t,
    int* __restrict__ off, int* __restrict__ perm,
    int* __restrict__ done, int* __restrict__ bar,
    float* __restrict__ partials, float* __restrict__ out) {
  // 48 KB shared buffer, overlaid per phase (union keeps 3 blocks/CU).
  __shared__ __align__(16) unsigned char smem[49152];

  int nt = blockIdx.x;                  // n-tile 0..7 (pins n-slice to one XCD)
  int mtb = blockIdx.y;                 // m-tile 0..71
  int bid = nt + 8 * mtb;               // 0..575
  int t = threadIdx.x;

  // ================= Phase P: prep =================
  if (bid == 0) {
    // ---- routing (single block, 256 threads, 4 waves) ----
    int (*hist)[En] = (int (*)[En])(smem);          // 128 B
    int (*rbas)[En] = (int (*)[En])(smem + 128);    // 128 B
    int* eoff = (int*)(smem + 256);                 // 36 B
    int wv = t >> 6;
    if (t < 4 * En) ((int*)hist)[t] = 0;
#pragma unroll
    for (int i = 0; i < PERM_N / 256; i++) perm[t + i * 256] = -1;  // pad fill
    __syncthreads();
    int e32[32], r32[32];
#pragma unroll
    for (int i = 0; i < 32; i++) {
      int e = sidx[t + i * 256];
      e32[i] = e;
      r32[i] = atomicAdd(&hist[wv][e], 1);
    }
    __syncthreads();
    if (t < En) {
      int s = 0;
      for (int w = 0; w < 4; w++) { rbas[w][t] = s; s += hist[w][t]; }
      hist[0][t] = s;
    }
    __syncthreads();
    if (t == 0) {
      int o = 0;
      for (int e = 0; e < En; e++) {
        eoff[e] = o; off[e] = o;
        o += (hist[0][e] + MT - 1) & ~(MT - 1);
      }
      eoff[En] = o; off[En] = o;
    }
    __syncthreads();
#pragma unroll
    for (int i = 0; i < 32; i++) {
      int e = e32[i];
      perm[eoff[e] + rbas[wv][e] + r32[i]] = t + i * 256;
    }
  } else {
    // blocks 1..575: ~10.7 units each
    for (int u = bid - 1; u < NUNITS; u += NBLK - 1) {
      if (u < NXB) {
        // ---- x fp32 -> bf16, natural order (no perm dependency) ----
        size_t idx = ((size_t)u * 256 + t) * 8;
        const float* src = x + idx;
        float4 a = *(const float4*)src;
        float4 b = *(const float4*)(src + 4);
        ushort8 o;
        o[0] = f2bf(a.x); o[1] = f2bf(a.y); o[2] = f2bf(a.z); o[3] = f2bf(a.w);
        o[4] = f2bf(b.x); o[5] = f2bf(b.y); o[6] = f2bf(b.z); o[7] = f2bf(b.w);
        *(ushort8*)(xb + idx) = o;
      } else {
        // ---- W1 [E][D][H] fp32 -> W1t [E][H][D] bf16, 64x64 LDS transpose ----
        __syncthreads();                 // protect tile reuse across unit loop
        float (*tile)[65] = (float (*)[65])(smem);   // 16,640 B
        int wb = u - NXB;
        int e = wb >> 8;
        int k0 = ((wb >> 4) & 15) * 64;   // D
        int n0 = (wb & 15) * 64;          // H
        int c4 = (t & 15) * 4;
        int r0 = t >> 4;                  // 0..15
        const float* src = W1 + ((size_t)e << 20) + (size_t)k0 * Hn + n0;
#pragma unroll
        for (int i = 0; i < 4; i++) {
          int r = r0 + i * 16;
          float4 v = *(const float4*)(src + (size_t)r * Hn + c4);
          tile[r][c4 + 0] = v.x; tile[r][c4 + 1] = v.y;
          tile[r][c4 + 2] = v.z; tile[r][c4 + 3] = v.w;
        }
        __syncthreads();
        u16* dst = w1t + ((size_t)e << 20) + (size_t)n0 * Dn + k0;
#pragma unroll
        for (int i = 0; i < 4; i++) {
          int h = r0 + i * 16;
          ushort4 o;
          o.x = f2bf(tile[c4 + 0][h]);
          o.y = f2bf(tile[c4 + 1][h]);
          o.z = f2bf(tile[c4 + 2][h]);
          o.w = f2bf(tile[c4 + 3][h]);
          *(ushort4*)(dst + (size_t)h * Dn + c4) = o;
        }
      }
    }
  }

  // ================= grid barrier (single-use, count-up) =================
  __syncthreads();
  if (t == 0) {
    __threadfence();                     // release: my block's xb/w1t/perm/off
    __hip_atomic_fetch_add(&bar[0], 1, __ATOMIC_RELAXED, __HIP_MEMORY_SCOPE_AGENT);
    while (__hip_atomic_load(&bar[0], __ATOMIC_RELAXED, __HIP_MEMORY_SCOPE_AGENT) < NBLK)
      __builtin_amdgcn_s_sleep(8);
    __threadfence();                     // acquire: others' writes
  }
  __syncthreads();

  // ================= Phase G: grouped GEMM (r0-verbatim inner loops) =====
  int n0g = nt * 128;
  int row0 = mtb * MT;
  bool live = (row0 < off[En]);
  if (live) {
    u16 (*As)[4096] = (u16 (*)[4096])(smem);           // 3 x 8 KB
    u16 (*Bs)[4096] = (u16 (*)[4096])(smem + 24576);   // 3 x 8 KB
    int e = 0;
    while (row0 >= off[e + 1]) e++;

    int lane = t & 63, w = t >> 6;
    int wm = w >> 1, wn = w & 1;

    // staging: HW puts lane L at LDS base + L*16B -> (row L>>2, slot L&3).
    // source chunk q = slot ^ swz(row) implements the xor swizzle.
    int srow = lane >> 2;
    int slot = lane & 3;
    int scol = (slot ^ ((srow >> 1) & 3)) * 8;
    const u16* aG[2]; const u16* bG[2];
    int lOff[2];
#pragma unroll
    for (int j = 0; j < 2; j++) {
      int rl = 32 * w + 16 * j + srow;
      int tok = perm[row0 + rl];
      if (tok < 0) tok = 0;               // pad row: any valid row (discarded)
      aG[j] = xb + ((size_t)tok << 10) + scol;
      bG[j] = w1t + ((size_t)e << 20) + (size_t)(n0g + rl) * Dn + scol;
      lOff[j] = (32 * w + 16 * j) * 32;   // wave-uniform LDS base (elements)
    }

    f32x4 acc[4][4];
#pragma unroll
    for (int i = 0; i < 4; i++)
#pragma unroll
      for (int j = 0; j < 4; j++)
        acc[i][j] = (f32x4){0.f, 0.f, 0.f, 0.f};

    int fr = lane & 15;
    int qf = lane >> 4;
    int qs = (qf ^ ((fr >> 1) & 3)) * 8;
    int offA[4], offB[4];
#pragma unroll
    for (int i = 0; i < 4; i++)
      offA[i] = (wm * 64 + i * 16 + fr) * 32 + qs;
#pragma unroll
    for (int j = 0; j < 4; j++)
      offB[j] = (wn * 64 + j * 16 + fr) * 32 + qs;

    // prologue: stages 0,1 in flight
#pragma unroll
    for (int it = 0; it < 2; it++) {
      int ko = it * 32;
      gld16(aG[0] + ko, (u16*)As[it] + lOff[0]);
      gld16(aG[1] + ko, (u16*)As[it] + lOff[1]);
      gld16(bG[0] + ko, (u16*)Bs[it] + lOff[0]);
      gld16(bG[1] + ko, (u16*)Bs[it] + lOff[1]);
    }

#pragma unroll
    for (int i = 0; i < 31; i++) {
      PIPE_BARRIER_VM4();               // stage-i loads done; stage-(i+1) in flight
      if (i + 2 < 32) {
        int s = (i + 2) % 3;
        int ko = (i + 2) * 32;
        gld16(aG[0] + ko, (u16*)As[s] + lOff[0]);
        gld16(aG[1] + ko, (u16*)As[s] + lOff[1]);
        gld16(bG[0] + ko, (u16*)Bs[s] + lOff[0]);
        gld16(bG[1] + ko, (u16*)Bs[s] + lOff[1]);
      }
      const u16* Ab = (const u16*)As[i % 3];
      const u16* Bb = (const u16*)Bs[i % 3];
      bf16x8 af[4], bfr[4];
#pragma unroll
      for (int ii = 0; ii < 4; ii++) af[ii] = *(const bf16x8*)(Ab + offA[ii]);
#pragma unroll
      for (int jj = 0; jj < 4; jj++) bfr[jj] = *(const bf16x8*)(Bb + offB[jj]);
#pragma unroll
      for (int ii = 0; ii < 4; ii++)
#pragma unroll
        for (int jj = 0; jj < 4; jj++)
          acc[ii][jj] = __builtin_amdgcn_mfma_f32_16x16x32_bf16(af[ii], bfr[jj], acc[ii][jj], 0, 0, 0);
    }
    {                                   // peeled last iteration (full drain)
      PIPE_BARRIER_VM0();
      const u16* Ab = (const u16*)As[31 % 3];
      const u16* Bb = (const u16*)Bs[31 % 3];
      bf16x8 af[4], bfr[4];
#pragma unroll
      for (int ii = 0; ii < 4; ii++) af[ii] = *(const bf16x8*)(Ab + offA[ii]);
#pragma unroll
      for (int jj = 0; jj < 4; jj++) bfr[jj] = *(const bf16x8*)(Bb + offB[jj]);
#pragma unroll
      for (int ii = 0; ii < 4; ii++)
#pragma unroll
        for (int jj = 0; jj < 4; jj++)
          acc[ii][jj] = __builtin_amdgcn_mfma_f32_16x16x32_bf16(af[ii], bfr[jj], acc[ii][jj], 0, 0, 0);
    }

    // epilogue: h = relu(acc + b1); partial = h . W2[e][col][0..3]
    int fq = lane >> 4;
    float4 w2v[4]; float b1v[4];
#pragma unroll
    for (int j = 0; j < 4; j++) {
      int col = n0g + wn * 64 + j * 16 + fr;
      w2v[j] = *(const float4*)(w2 + ((size_t)e * Hn + col) * 4);
      b1v[j] = b1[(size_t)e * Hn + col];
    }
    int chunk = nt * 2 + wn;            // 64-col chunk 0..15
#pragma unroll
    for (int i = 0; i < 4; i++) {
      int rbase = wm * 64 + i * 16 + fq * 4;
#pragma unroll
      for (int r = 0; r < 4; r++) {
        float s0 = 0.f, s1 = 0.f, s2 = 0.f, s3 = 0.f;
#pragma unroll
        for (int j = 0; j < 4; j++) {
          float h = acc[i][j][r] + b1v[j];
          h = fmaxf(h, 0.f);
          s0 = fmaf(h, w2v[j].x, s0);
          s1 = fmaf(h, w2v[j].y, s1);
          s2 = fmaf(h, w2v[j].z, s2);
          s3 = fmaf(h, w2v[j].w, s3);
        }
#pragma unroll
        for (int m = 1; m < 16; m <<= 1) {
          s0 += __shfl_xor(s0, m);
          s1 += __shfl_xor(s1, m);
          s2 += __shfl_xor(s2, m);
          s3 += __shfl_xor(s3, m);
        }
        if (fr == 0) {
          int row = row0 + rbase + r;
          *(float4*)(partials + ((size_t)row * NB + chunk) * 4) =
              make_float4(s0, s1, s2, s3);
        }
      }
    }

    // ======== ticket: 8th finisher of this m-tile computes probs ========
    __threadfence();                    // release my partials (device scope)
    __syncthreads();                    // all threads' stores+fences done
    int* win = (int*)smem;              // LDS reuse (gemm done with As/Bs)
    if (t == 0) {
      int k = __hip_atomic_fetch_add(&done[mtb], 1, __ATOMIC_SEQ_CST,
                                     __HIP_MEMORY_SCOPE_AGENT);
      *win = (k == 7) ? 1 : 0;
    }
    __syncthreads();
    if (*win) {
      __threadfence();                  // acquire the other 7 blocks' partials
      if (t < MT) {
        int p = row0 + t;
        int tok = perm[p];
        if (tok >= 0) {
          int ex = sidx[tok];
          float s0 = 0.f, s1 = 0.f, s2 = 0.f, s3 = 0.f;
#pragma unroll
          for (int nb = 0; nb < NB; nb++) {
            float4 v = *(const float4*)(partials + ((size_t)p * NB + nb) * 4);
            s0 += v.x; s1 += v.y; s2 += v.z; s3 += v.w;
          }
          float l0 = s0 + b2[ex * 4 + 0];
          float l1 = s1 + b2[ex * 4 + 1];
          float l2 = s2 + b2[ex * 4 + 2];
          float l3 = s3 + b2[ex * 4 + 3];
          out[tok * 4 + 0] = l0; out[tok * 4 + 1] = l1;
          out[tok * 4 + 2] = l2; out[tok * 4 + 3] = l3;
          float q0 = 1.f / (1.f + expf(-l0));
          float q1 = 1.f / (1.f + expf(-l1));
          float q2 = 1.f / (1.f + expf(-l2));
          float q3 = 1.f / (1.f + expf(-l3));
          const float eps = 1e-8f;
          float p0 = fmaxf(1.f - q0, eps);
          float p1 = fmaxf(q0 - q1, eps);
          float p2 = fmaxf(q1 - q2, eps);
          float p3 = fmaxf(q2 - q3, eps);
          float p4 = fmaxf(q3, eps);
          float s = p0 + p1 + p2 + p3 + p4;
          float inv = 1.f / fmaxf(s, eps);
          float* pr = out + (size_t)Bn * 4 + (size_t)tok * 5;
          pr[0] = p0 * inv; pr[1] = p1 * inv; pr[2] = p2 * inv;
          pr[3] = p3 * inv; pr[4] = p4 * inv;
        }
      }
    }
  }
}

// ---------- launch ----------
extern "C" void kernel_launch(void* const* d_in, const int* in_sizes, int n_in,
                              void* d_out, int out_size, void* d_ws, size_t ws_size,
                              hipStream_t stream) {
  const float* x  = (const float*)d_in[0];
  const int* sidx = (const int*)d_in[1];
  const float* W1 = (const float*)d_in[2];
  const float* b1 = (const float*)d_in[3];
  const float* W2 = (const float*)d_in[4];
  const float* b2 = (const float*)d_in[5];
  float* out = (float*)d_out;

  uint8_t* w = (uint8_t*)d_ws;
  int* done = (int*)(w + 0);      // 72 ints
  int* bar  = (int*)(w + 288);    // 2 ints
  int* off  = (int*)(w + 320);    // 9 ints
  int* perm = (int*)(w + 512);    // 9216 ints (ends at 37376)
  u16* xb      = (u16*)(w + 40960);                    // 16,777,216 B
  u16* w1t     = (u16*)(w + 40960 + 16777216);         // 16,777,216 B
  float* parts = (float*)(w + 40960 + 2 * 16777216);   // 2,359,296 B

  // zero done[] + bar[] (captured as a memset node; off/perm rewritten by routing)
  hipMemsetAsync(w, 0, 512, stream);
  fused_k<<<dim3(8, MTILES), 256, 0, stream>>>(
      x, sidx, W1, b1, W2, b2, xb, w1t, off, perm, done, bar, parts, out);
}

// Round 6
// 176.667 us; speedup vs baseline: 1.7241x; 1.7241x over previous
//
#include <hip/hip_runtime.h>
#include <cstdint>
#include <cstddef>

#define Bn 8192
#define Dn 1024
#define Hn 1024
#define En 8
#define MT 128                     // expert padding quantum / m-tile
#define PERM_N (Bn + En * MT)      // 9216
#define MTILES (PERM_N / MT)       // 72
#define NB 16                      // 64-col partial chunks per row
#define NWB 2048                   // W1-transpose blocks (prep blocks 1..2048)

typedef unsigned short u16;
typedef __bf16 bf16x8 __attribute__((ext_vector_type(8)));
typedef float f32x4 __attribute__((ext_vector_type(4)));
typedef unsigned short ushort8 __attribute__((ext_vector_type(8)));

// ---------- helpers ----------
__device__ __forceinline__ u16 f2bf(float f) {
  unsigned int u = __float_as_uint(f);
  unsigned int r = u + 0x7fffu + ((u >> 16) & 1u);   // RNE
  return (u16)(r >> 16);
}

__device__ __forceinline__ void gld16(const void* g, void* l) {
  __builtin_amdgcn_global_load_lds(
      (const __attribute__((address_space(1))) void*)g,
      (__attribute__((address_space(3))) void*)l, 16, 0, 0);
}

// ---------- D1: routing (block 0) + W1^T (1..2048) ----------
// W1 [E][D][H] fp32 -> W1t [E][H][D] bf16 (r0-proven body)
__global__ __launch_bounds__(256) void prep_k(
    const int* __restrict__ sidx, const float* __restrict__ W1,
    u16* __restrict__ w1t, int* __restrict__ off, int* __restrict__ perm) {
  int bid = blockIdx.x;
  int t = threadIdx.x;

  if (bid == 0) {
    // ---- routing (single block, 256 threads, 4 waves) ----
    __shared__ int hist[4][En];
    __shared__ int base[4][En];
    __shared__ int eoff[En + 1];
    int wv = t >> 6;
    if (t < 4 * En) ((int*)hist)[t] = 0;
#pragma unroll
    for (int i = 0; i < PERM_N / 256; i++) perm[t + i * 256] = -1;  // pad fill
    __syncthreads();
    int e32[32], r32[32];
#pragma unroll
    for (int i = 0; i < 32; i++) {
      int e = sidx[t + i * 256];
      e32[i] = e;
      r32[i] = atomicAdd(&hist[wv][e], 1);
    }
    __syncthreads();
    if (t < En) {
      int s = 0;
      for (int w = 0; w < 4; w++) { base[w][t] = s; s += hist[w][t]; }
      hist[0][t] = s;
    }
    __syncthreads();
    if (t == 0) {
      int o = 0;
      for (int e = 0; e < En; e++) {
        eoff[e] = o; off[e] = o;
        o += (hist[0][e] + MT - 1) & ~(MT - 1);
      }
      eoff[En] = o; off[En] = o;
    }
    __syncthreads();
#pragma unroll
    for (int i = 0; i < 32; i++) {
      int e = e32[i];
      perm[eoff[e] + base[wv][e] + r32[i]] = t + i * 256;
    }
  } else {
    // ---- W1 [E][D][H] fp32 -> W1t [E][H][D] bf16, 64x64 LDS transpose ----
    __shared__ float tile[64][65];
    int wb = bid - 1;
    int e = wb >> 8;
    int k0 = ((wb >> 4) & 15) * 64;   // D
    int n0 = (wb & 15) * 64;          // H
    int c4 = (t & 15) * 4;
    int r0 = t >> 4;                  // 0..15
    const float* src = W1 + ((size_t)e << 20) + (size_t)k0 * Hn + n0;
#pragma unroll
    for (int i = 0; i < 4; i++) {
      int r = r0 + i * 16;
      float4 v = *(const float4*)(src + (size_t)r * Hn + c4);
      tile[r][c4 + 0] = v.x; tile[r][c4 + 1] = v.y;
      tile[r][c4 + 2] = v.z; tile[r][c4 + 3] = v.w;
    }
    __syncthreads();
    u16* dst = w1t + ((size_t)e << 20) + (size_t)n0 * Dn + k0;
#pragma unroll
    for (int i = 0; i < 4; i++) {
      int h = r0 + i * 16;
      ushort4 o;
      o.x = f2bf(tile[c4 + 0][h]);
      o.y = f2bf(tile[c4 + 1][h]);
      o.z = f2bf(tile[c4 + 2][h]);
      o.w = f2bf(tile[c4 + 3][h]);
      *(ushort4*)(dst + (size_t)h * Dn + c4) = o;
    }
  }
}

// ---------- D2: grouped GEMM, 128x128, double-buffered, all-__syncthreads.
// A: x fp32 perm-gather -> in-register f2bf -> ds_write (same LDS layout/swizzle
//    r0's gld16 produced). B: gld16 from w1t bf16 (r0-verbatim).
__global__ __launch_bounds__(256) void gemm_k(
    const float* __restrict__ x, const u16* __restrict__ w1t,
    const float* __restrict__ b1, const float* __restrict__ w2,
    const int* __restrict__ off, const int* __restrict__ perm,
    float* __restrict__ partials) {
  __shared__ u16 As[2][4096];   // 2 x 128 rows x 32 k (8 KB each)
  __shared__ u16 Bs[2][4096];

  int n0 = blockIdx.x * 128;            // x = n-tile: pins n-slice to one XCD
  int row0 = blockIdx.y * MT;
  if (row0 >= off[En]) return;          // dead (all-pad) tile
  int e = 0;
  while (row0 >= off[e + 1]) e++;

  int tid = threadIdx.x;
  int lane = tid & 63, w = tid >> 6;
  int wm = w >> 1, wn = w & 1;

  // staging geometry (identical lane->(row,chunk) map as r0):
  // lane L handles row rl = 32w+16j+(L>>2), chunk slot L&3; source chunk
  // q = slot ^ swz(row) implements the xor swizzle.
  int srow = lane >> 2;
  int slot = lane & 3;
  int scol = (slot ^ ((srow >> 1) & 3)) * 8;   // element offset within 32-k row
  const float* aF[2];                   // A: f32 source rows (perm gather)
  const u16* bG[2];                     // B: bf16 source rows
  int lOff[2];                          // wave-uniform LDS base (elements)
  int aW[2];                            // per-lane LDS write elem offset (A)
#pragma unroll
  for (int j = 0; j < 2; j++) {
    int rl = 32 * w + 16 * j + srow;
    int tok = perm[row0 + rl];
    if (tok < 0) tok = 0;               // pad row: any valid row (result discarded)
    aF[j] = x + ((size_t)tok << 10) + scol;
    bG[j] = w1t + ((size_t)e << 20) + (size_t)(n0 + rl) * Dn + scol;
    lOff[j] = (32 * w + 16 * j) * 32;
    aW[j] = lOff[j] + lane * 8;         // == row-major (rl,slot) dest, 8 elems
  }

  f32x4 acc[4][4];
#pragma unroll
  for (int i = 0; i < 4; i++)
#pragma unroll
    for (int j = 0; j < 4; j++)
      acc[i][j] = (f32x4){0.f, 0.f, 0.f, 0.f};

  int fr = lane & 15;
  int qf = lane >> 4;
  int qs = (qf ^ ((fr >> 1) & 3)) * 8;
  int offA[4], offB[4];
#pragma unroll
  for (int i = 0; i < 4; i++)
    offA[i] = (wm * 64 + i * 16 + fr) * 32 + qs;
#pragma unroll
  for (int j = 0; j < 4; j++)
    offB[j] = (wn * 64 + j * 16 + fr) * 32 + qs;

  float4 av0, av1, av2, av3;            // A prefetch regs (8 f32 per slot j)

#define LOAD_A(st) do {                                               \
    int _ko = (st) * 32;                                              \
    av0 = *(const float4*)(aF[0] + _ko);                              \
    av1 = *(const float4*)(aF[0] + _ko + 4);                          \
    av2 = *(const float4*)(aF[1] + _ko);                              \
    av3 = *(const float4*)(aF[1] + _ko + 4);                          \
  } while (0)

#define WRITE_A(st) do {                                              \
    int _s = (st) & 1;                                                \
    ushort8 o;                                                        \
    o[0] = f2bf(av0.x); o[1] = f2bf(av0.y);                           \
    o[2] = f2bf(av0.z); o[3] = f2bf(av0.w);                           \
    o[4] = f2bf(av1.x); o[5] = f2bf(av1.y);                           \
    o[6] = f2bf(av1.z); o[7] = f2bf(av1.w);                           \
    *(ushort8*)((u16*)As[_s] + aW[0]) = o;                            \
    o[0] = f2bf(av2.x); o[1] = f2bf(av2.y);                           \
    o[2] = f2bf(av2.z); o[3] = f2bf(av2.w);                           \
    o[4] = f2bf(av3.x); o[5] = f2bf(av3.y);                           \
    o[6] = f2bf(av3.z); o[7] = f2bf(av3.w);                           \
    *(ushort8*)((u16*)As[_s] + aW[1]) = o;                            \
  } while (0)

#define STAGE_B(st) do {                                              \
    int _s = (st) & 1;                                                \
    int _ko = (st) * 32;                                              \
    gld16(bG[0] + _ko, (u16*)Bs[_s] + lOff[0]);                       \
    gld16(bG[1] + _ko, (u16*)Bs[_s] + lOff[1]);                       \
  } while (0)

#define COMPUTE(st) do {                                              \
    const u16* Ab = (const u16*)As[(st) & 1];                         \
    const u16* Bb = (const u16*)Bs[(st) & 1];                         \
    bf16x8 af[4], bfr[4];                                             \
    _Pragma("unroll")                                                 \
    for (int ii = 0; ii < 4; ii++) af[ii] = *(const bf16x8*)(Ab + offA[ii]); \
    _Pragma("unroll")                                                 \
    for (int jj = 0; jj < 4; jj++) bfr[jj] = *(const bf16x8*)(Bb + offB[jj]); \
    _Pragma("unroll")                                                 \
    for (int ii = 0; ii < 4; ii++)                                    \
      _Pragma("unroll")                                               \
      for (int jj = 0; jj < 4; jj++)                                  \
        acc[ii][jj] = __builtin_amdgcn_mfma_f32_16x16x32_bf16(af[ii], bfr[jj], acc[ii][jj], 0, 0, 0); \
  } while (0)

  // prologue: stage 0 fully materialized, stage-1 A-regs in flight
  LOAD_A(0);
  STAGE_B(0);
  WRITE_A(0);                           // compiler waits on av* loads here
  LOAD_A(1);
  __syncthreads();                      // drains: B(0) gld16 + A(0) ds_writes + A(1) loads

  // steady state: iter i — write stage i+1 (regs loaded in iter i-1),
  // issue B(i+1) + A-load(i+2), compute stage i, full-drain barrier.
#pragma unroll
  for (int i = 0; i < 32; i++) {
    if (i + 1 < 32) {
      STAGE_B(i + 1);
      WRITE_A(i + 1);
      if (i + 2 < 32) LOAD_A(i + 2);
    }
    COMPUTE(i);
    if (i + 1 < 32) __syncthreads();    // __syncthreads drains vmcnt+lgkmcnt
  }

#undef LOAD_A
#undef WRITE_A
#undef STAGE_B
#undef COMPUTE

  // epilogue: h = relu(acc + b1); partial = h . W2[e][col][0..3]; float4 per row/chunk
  int fq = lane >> 4;
  float4 w2v[4]; float b1v[4];
#pragma unroll
  for (int j = 0; j < 4; j++) {
    int col = n0 + wn * 64 + j * 16 + fr;
    w2v[j] = *(const float4*)(w2 + ((size_t)e * Hn + col) * 4);
    b1v[j] = b1[(size_t)e * Hn + col];
  }
  int chunk = blockIdx.x * 2 + wn;      // 64-col chunk 0..15
#pragma unroll
  for (int i = 0; i < 4; i++) {
    int rbase = wm * 64 + i * 16 + fq * 4;
#pragma unroll
    for (int r = 0; r < 4; r++) {
      float s0 = 0.f, s1 = 0.f, s2 = 0.f, s3 = 0.f;
#pragma unroll
      for (int j = 0; j < 4; j++) {
        float h = acc[i][j][r] + b1v[j];
        h = fmaxf(h, 0.f);
        s0 = fmaf(h, w2v[j].x, s0);
        s1 = fmaf(h, w2v[j].y, s1);
        s2 = fmaf(h, w2v[j].z, s2);
        s3 = fmaf(h, w2v[j].w, s3);
      }
#pragma unroll
      for (int m = 1; m < 16; m <<= 1) {
        s0 += __shfl_xor(s0, m);
        s1 += __shfl_xor(s1, m);
        s2 += __shfl_xor(s2, m);
        s3 += __shfl_xor(s3, m);
      }
      if (fr == 0) {
        int row = row0 + rbase + r;
        *(float4*)(partials + ((size_t)row * NB + chunk) * 4) =
            make_float4(s0, s1, s2, s3);
      }
    }
  }
}

// ---------- D3: reduce partials + ordinal probs ----------
__global__ void probs_k(const float* __restrict__ partials,
                        const int* __restrict__ perm, const int* __restrict__ off,
                        const int* __restrict__ sidx, const float* __restrict__ b2,
                        float* __restrict__ out) {
  int p = blockIdx.x * blockDim.x + threadIdx.x;
  if (p >= off[En]) return;
  int tok = perm[p];
  if (tok < 0) return;
  int e = sidx[tok];
  float s0 = 0.f, s1 = 0.f, s2 = 0.f, s3 = 0.f;
#pragma unroll
  for (int nb = 0; nb < NB; nb++) {
    float4 v = *(const float4*)(partials + ((size_t)p * NB + nb) * 4);
    s0 += v.x; s1 += v.y; s2 += v.z; s3 += v.w;
  }
  float l0 = s0 + b2[e * 4 + 0];
  float l1 = s1 + b2[e * 4 + 1];
  float l2 = s2 + b2[e * 4 + 2];
  float l3 = s3 + b2[e * 4 + 3];
  out[tok * 4 + 0] = l0; out[tok * 4 + 1] = l1;
  out[tok * 4 + 2] = l2; out[tok * 4 + 3] = l3;
  float q0 = 1.f / (1.f + expf(-l0));
  float q1 = 1.f / (1.f + expf(-l1));
  float q2 = 1.f / (1.f + expf(-l2));
  float q3 = 1.f / (1.f + expf(-l3));
  const float eps = 1e-8f;
  float p0 = fmaxf(1.f - q0, eps);
  float p1 = fmaxf(q0 - q1, eps);
  float p2 = fmaxf(q1 - q2, eps);
  float p3 = fmaxf(q2 - q3, eps);
  float p4 = fmaxf(q3, eps);
  float s = p0 + p1 + p2 + p3 + p4;
  float inv = 1.f / fmaxf(s, eps);
  float* pr = out + (size_t)Bn * 4 + (size_t)tok * 5;
  pr[0] = p0 * inv; pr[1] = p1 * inv; pr[2] = p2 * inv;
  pr[3] = p3 * inv; pr[4] = p4 * inv;
}

// ---------- launch ----------
extern "C" void kernel_launch(void* const* d_in, const int* in_sizes, int n_in,
                              void* d_out, int out_size, void* d_ws, size_t ws_size,
                              hipStream_t stream) {
  const float* x  = (const float*)d_in[0];
  const int* sidx = (const int*)d_in[1];
  const float* W1 = (const float*)d_in[2];
  const float* b1 = (const float*)d_in[3];
  const float* W2 = (const float*)d_in[4];
  const float* b2 = (const float*)d_in[5];
  float* out = (float*)d_out;

  uint8_t* w = (uint8_t*)d_ws;
  int* off  = (int*)(w + 64);     // 9 ints
  int* perm = (int*)(w + 512);    // 9216 ints
  u16* w1t     = (u16*)(w + 40960);                    // 16,777,216 B
  float* parts = (float*)(w + 40960 + 16777216);       // 2,359,296 B

  prep_k<<<1 + NWB, 256, 0, stream>>>(sidx, W1, w1t, off, perm);
  gemm_k<<<dim3(Hn / 128, MTILES), 256, 0, stream>>>(x, w1t, b1, W2, off, perm, parts);
  probs_k<<<(PERM_N + 255) / 256, 256, 0, stream>>>(parts, perm, off, sidx, b2, out);
}

// Round 8
// 159.233 us; speedup vs baseline: 1.9129x; 1.1095x over previous
//
#include <hip/hip_runtime.h>
#include <cstdint>
#include <cstddef>

#define Bn 8192
#define Dn 1024
#define Hn 1024
#define En 8
#define MT 128                     // expert padding quantum / m-tile
#define PERM_N (Bn + En * MT)      // 9216
#define MTILES (PERM_N / MT)       // 72
#define NB 16                      // 64-col partial chunks per row
#define KC 32                      // k elements per pipeline stage
#define NKC (Dn / KC)              // 32 stages
#define TSTRIDE (MT * KC)          // 4096 u16 per (tile, k-chunk)
#define MT_STRIDE (NKC * TSTRIDE)  // 131072 u16 per 128-row layout tile

typedef unsigned short u16;
typedef __bf16 bf16x8 __attribute__((ext_vector_type(8)));
typedef float f32x4 __attribute__((ext_vector_type(4)));
typedef unsigned short ushort8 __attribute__((ext_vector_type(8)));

// ---------- helpers ----------
__device__ __forceinline__ u16 f2bf(float f) {
  unsigned int u = __float_as_uint(f);
  unsigned int r = u + 0x7fffu + ((u >> 16) & 1u);   // RNE
  return (u16)(r >> 16);
}

__device__ __forceinline__ void gld16(const void* g, void* l) {
  __builtin_amdgcn_global_load_lds(
      (const __attribute__((address_space(1))) void*)g,
      (__attribute__((address_space(3))) void*)l, 16, 0, 0);
}

// wait for own vmcnt<=N (lgkm/exp untouched), then workgroup barrier.
// imm: vmcnt[3:0] | expcnt[6:4] | lgkmcnt[11:8]
#define PIPE_BARRIER_VM4() do {                    \
    asm volatile("" ::: "memory");                 \
    __builtin_amdgcn_s_waitcnt(0x0F74);            \
    __builtin_amdgcn_s_barrier();                  \
    asm volatile("" ::: "memory");                 \
  } while (0)
#define PIPE_BARRIER_VM0() do {                    \
    asm volatile("" ::: "memory");                 \
    __builtin_amdgcn_s_waitcnt(0x0F70);            \
    __builtin_amdgcn_s_barrier();                  \
    asm volatile("" ::: "memory");                 \
  } while (0)

// ---------- P1: routing (block 0) + W1 -> tile-major bf16 (blocks 1..2048)
// w1tT layout: [e][h>>7][kc(32)][h&127][k&31] u16   (r1-verbatim, proven)
__global__ __launch_bounds__(256) void prep_r(
    const int* __restrict__ sidx, const float* __restrict__ W1,
    u16* __restrict__ w1tT, int* __restrict__ off, int* __restrict__ perm) {
  int bid = blockIdx.x;
  int t = threadIdx.x;

  if (bid == 0) {
    // ---- routing (single block, 256 threads, 4 waves) ----
    __shared__ int hist[4][En];
    __shared__ int base[4][En];
    __shared__ int eoff[En + 1];
    int wv = t >> 6;
    if (t < 4 * En) ((int*)hist)[t] = 0;
#pragma unroll
    for (int i = 0; i < PERM_N / 256; i++) perm[t + i * 256] = -1;  // pad fill
    __syncthreads();
    int e32[32], r32[32];
#pragma unroll
    for (int i = 0; i < 32; i++) {
      int e = sidx[t + i * 256];
      e32[i] = e;
      r32[i] = atomicAdd(&hist[wv][e], 1);
    }
    __syncthreads();
    if (t < En) {
      int s = 0;
      for (int w = 0; w < 4; w++) { base[w][t] = s; s += hist[w][t]; }
      hist[0][t] = s;
    }
    __syncthreads();
    if (t == 0) {
      int o = 0;
      for (int e = 0; e < En; e++) {
        eoff[e] = o; off[e] = o;
        o += (hist[0][e] + MT - 1) & ~(MT - 1);
      }
      eoff[En] = o; off[En] = o;
    }
    __syncthreads();
#pragma unroll
    for (int i = 0; i < 32; i++) {
      int e = e32[i];
      perm[eoff[e] + base[wv][e] + r32[i]] = t + i * 256;
    }
  } else {
    // ---- W1 [E][D][H] fp32 -> tile-major bf16, 64x64 LDS transpose ----
    __shared__ float tile[64][65];
    int wb = bid - 1;
    int e = wb >> 8;
    int k0 = ((wb >> 4) & 15) * 64;   // D (contraction) dim
    int n0 = (wb & 15) * 64;          // H dim
    int c4 = (t & 15) * 4;
    int r0 = t >> 4;                  // 0..15
    const float* src = W1 + ((size_t)e << 20) + (size_t)k0 * Hn + n0;
#pragma unroll
    for (int i = 0; i < 4; i++) {
      int r = r0 + i * 16;
      float4 v = *(const float4*)(src + (size_t)r * Hn + c4);
      tile[r][c4 + 0] = v.x; tile[r][c4 + 1] = v.y;
      tile[r][c4 + 2] = v.z; tile[r][c4 + 3] = v.w;
    }
    __syncthreads();
    u16* dstE = w1tT + ((size_t)e << 20);
#pragma unroll
    for (int i = 0; i < 4; i++) {
      int hl = r0 + i * 16;           // 0..63 local H
      int gh = n0 + hl;               // global H row
      int gk = k0 + c4;               // global K (chunk boundary safe: c4%4==0)
      size_t addr = ((size_t)(gh >> 7) * NKC + (gk >> 5)) * TSTRIDE
                  + (size_t)(gh & 127) * KC + (gk & 31);
      ushort4 o;
      o.x = f2bf(tile[c4 + 0][hl]);
      o.y = f2bf(tile[c4 + 1][hl]);
      o.z = f2bf(tile[c4 + 2][hl]);
      o.w = f2bf(tile[c4 + 3][hl]);
      *(ushort4*)(dstE + addr) = o;
    }
  }
}

// ---------- P2: x fp32 -> permuted tile-major bf16 (fine-grained streaming)
// xbT layout: [mtile(72)][kchunk(32)][row 128][k 32] u16, natural (no swizzle).
// 4608 blocks x 2 perm-rows; thread = 8 elems; row reads 4KB contiguous.
__global__ __launch_bounds__(256) void pack_x(
    const float* __restrict__ x, const int* __restrict__ perm,
    u16* __restrict__ xbT) {
  int blk = blockIdx.x;             // 0..4607
  int t = threadIdx.x;
  __shared__ int toks[2];
  if (t < 2) {
    int p = perm[blk * 2 + t];
    toks[t] = p < 0 ? 0 : p;        // pad row: any valid row (result discarded)
  }
  __syncthreads();
  int p0 = blk * 2;
  int mt = p0 >> 7;                 // 2-row group never crosses a 128-row tile
  int rl0 = p0 & 127;
  int idx = t * 8;                  // 0..2047
  int rloc = idx >> 10;             // 0 or 1
  int pos = idx & 1023;             // elem within row
  int kc = pos >> 5;
  int k0 = pos & 31;
  const float* src = x + ((size_t)toks[rloc] << 10) + pos;
  float4 a = *(const float4*)src;
  float4 b = *(const float4*)(src + 4);
  ushort8 o;
  o[0] = f2bf(a.x); o[1] = f2bf(a.y); o[2] = f2bf(a.z); o[3] = f2bf(a.w);
  o[4] = f2bf(b.x); o[5] = f2bf(b.y); o[6] = f2bf(b.z); o[7] = f2bf(b.w);
  *(ushort8*)(xbT + (size_t)mt * MT_STRIDE + (size_t)kc * TSTRIDE
              + (size_t)(rl0 + rloc) * KC + k0) = o;
}

// ---------- D2: grouped GEMM, 128x128, 3-stage vmcnt(4) pipeline,
// ---------- all-contiguous (homogeneous) tile-major staging — r1-verbatim ----
__global__ __launch_bounds__(256) void gemm_k(
    const u16* __restrict__ xbT, const u16* __restrict__ w1tT,
    const float* __restrict__ b1, const float* __restrict__ w2,
    const int* __restrict__ off, float* __restrict__ partials) {
  __shared__ u16 As[3][4096];   // 3 stages x 128 rows x 32 k (8 KB each)
  __shared__ u16 Bs[3][4096];

  int nt = blockIdx.x;                  // n-tile: pins n-slice to one XCD
  int mt = blockIdx.y;
  int row0 = mt * MT;
  if (row0 >= off[En]) return;          // dead (all-pad) tile
  int e = 0;
  while (row0 >= off[e + 1]) e++;

  int tid = threadIdx.x;
  int lane = tid & 63, w = tid >> 6;
  int wm = w >> 1, wn = w & 1;

  // staging: HW puts lane L at LDS base + L*16B -> (row L>>2, slot L&3).
  // source chunk q = slot ^ swz(row) implements the xor swizzle; source is
  // CONTIGUOUS per instruction (1 KB from the packed tile).
  int srow = lane >> 2;
  int slot = lane & 3;
  int sx = (slot ^ ((srow >> 1) & 3)) * 8;
  const u16* aBase = xbT + (size_t)mt * MT_STRIDE;
  const u16* bBase = w1tT + ((size_t)e << 20) + (size_t)nt * MT_STRIDE;
  int gOff[2], lOff[2];
#pragma unroll
  for (int j = 0; j < 2; j++) {
    int rl = 32 * w + 16 * j + srow;
    gOff[j] = rl * KC + sx;             // within a k-chunk tile
    lOff[j] = (32 * w + 16 * j) * KC;   // wave-uniform LDS base (elements)
  }

  f32x4 acc[4][4];
#pragma unroll
  for (int i = 0; i < 4; i++)
#pragma unroll
    for (int j = 0; j < 4; j++)
      acc[i][j] = (f32x4){0.f, 0.f, 0.f, 0.f};

  int fr = lane & 15;
  int qf = lane >> 4;
  int qs = (qf ^ ((fr >> 1) & 3)) * 8;
  int offA[4], offB[4];
#pragma unroll
  for (int i = 0; i < 4; i++)
    offA[i] = (wm * 64 + i * 16 + fr) * KC + qs;
#pragma unroll
  for (int j = 0; j < 4; j++)
    offB[j] = (wn * 64 + j * 16 + fr) * KC + qs;

  // prologue: stages 0,1 in flight
#pragma unroll
  for (int it = 0; it < 2; it++) {
    int ko = it * TSTRIDE;
    gld16(aBase + ko + gOff[0], (u16*)As[it] + lOff[0]);
    gld16(aBase + ko + gOff[1], (u16*)As[it] + lOff[1]);
    gld16(bBase + ko + gOff[0], (u16*)Bs[it] + lOff[0]);
    gld16(bBase + ko + gOff[1], (u16*)Bs[it] + lOff[1]);
  }

#pragma unroll
  for (int i = 0; i < 31; i++) {
    PIPE_BARRIER_VM4();                 // stage-i loads done; stage-(i+1) in flight
    if (i + 2 < 32) {
      int s = (i + 2) % 3;
      int ko = (i + 2) * TSTRIDE;
      gld16(aBase + ko + gOff[0], (u16*)As[s] + lOff[0]);
      gld16(aBase + ko + gOff[1], (u16*)As[s] + lOff[1]);
      gld16(bBase + ko + gOff[0], (u16*)Bs[s] + lOff[0]);
      gld16(bBase + ko + gOff[1], (u16*)Bs[s] + lOff[1]);
    }
    const u16* Ab = (const u16*)As[i % 3];
    const u16* Bb = (const u16*)Bs[i % 3];
    bf16x8 af[4], bfr[4];
#pragma unroll
    for (int ii = 0; ii < 4; ii++) af[ii] = *(const bf16x8*)(Ab + offA[ii]);
#pragma unroll
    for (int jj = 0; jj < 4; jj++) bfr[jj] = *(const bf16x8*)(Bb + offB[jj]);
#pragma unroll
    for (int ii = 0; ii < 4; ii++)
#pragma unroll
      for (int jj = 0; jj < 4; jj++)
        acc[ii][jj] = __builtin_amdgcn_mfma_f32_16x16x32_bf16(af[ii], bfr[jj], acc[ii][jj], 0, 0, 0);
  }
  {                                     // peeled last iteration (full drain)
    PIPE_BARRIER_VM0();
    const u16* Ab = (const u16*)As[31 % 3];
    const u16* Bb = (const u16*)Bs[31 % 3];
    bf16x8 af[4], bfr[4];
#pragma unroll
    for (int ii = 0; ii < 4; ii++) af[ii] = *(const bf16x8*)(Ab + offA[ii]);
#pragma unroll
    for (int jj = 0; jj < 4; jj++) bfr[jj] = *(const bf16x8*)(Bb + offB[jj]);
#pragma unroll
    for (int ii = 0; ii < 4; ii++)
#pragma unroll
      for (int jj = 0; jj < 4; jj++)
        acc[ii][jj] = __builtin_amdgcn_mfma_f32_16x16x32_bf16(af[ii], bfr[jj], acc[ii][jj], 0, 0, 0);
  }

  // epilogue: h = relu(acc + b1); partial = h . W2[e][col][0..3]
  int fq = lane >> 4;
  int n0 = nt * 128;
  float4 w2v[4]; float b1v[4];
#pragma unroll
  for (int j = 0; j < 4; j++) {
    int col = n0 + wn * 64 + j * 16 + fr;
    w2v[j] = *(const float4*)(w2 + ((size_t)e * Hn + col) * 4);
    b1v[j] = b1[(size_t)e * Hn + col];
  }
  int chunk = nt * 2 + wn;              // 64-col chunk 0..15
#pragma unroll
  for (int i = 0; i < 4; i++) {
    int rbase = wm * 64 + i * 16 + fq * 4;
#pragma unroll
    for (int r = 0; r < 4; r++) {
      float s0 = 0.f, s1 = 0.f, s2 = 0.f, s3 = 0.f;
#pragma unroll
      for (int j = 0; j < 4; j++) {
        float h = acc[i][j][r] + b1v[j];
        h = fmaxf(h, 0.f);
        s0 = fmaf(h, w2v[j].x, s0);
        s1 = fmaf(h, w2v[j].y, s1);
        s2 = fmaf(h, w2v[j].z, s2);
        s3 = fmaf(h, w2v[j].w, s3);
      }
#pragma unroll
      for (int m = 1; m < 16; m <<= 1) {
        s0 += __shfl_xor(s0, m);
        s1 += __shfl_xor(s1, m);
        s2 += __shfl_xor(s2, m);
        s3 += __shfl_xor(s3, m);
      }
      if (fr == 0) {
        int row = row0 + rbase + r;
        *(float4*)(partials + ((size_t)row * NB + chunk) * 4) =
            make_float4(s0, s1, s2, s3);
      }
    }
  }
}

// ---------- D3: reduce partials + ordinal probs ----------
__global__ void probs_k(const float* __restrict__ partials,
                        const int* __restrict__ perm, const int* __restrict__ off,
                        const int* __restrict__ sidx, const float* __restrict__ b2,
                        float* __restrict__ out) {
  int p = blockIdx.x * blockDim.x + threadIdx.x;
  if (p >= off[En]) return;
  int tok = perm[p];
  if (tok < 0) return;
  int e = sidx[tok];
  float s0 = 0.f, s1 = 0.f, s2 = 0.f, s3 = 0.f;
#pragma unroll
  for (int nb = 0; nb < NB; nb++) {
    float4 v = *(const float4*)(partials + ((size_t)p * NB + nb) * 4);
    s0 += v.x; s1 += v.y; s2 += v.z; s3 += v.w;
  }
  float l0 = s0 + b2[e * 4 + 0];
  float l1 = s1 + b2[e * 4 + 1];
  float l2 = s2 + b2[e * 4 + 2];
  float l3 = s3 + b2[e * 4 + 3];
  out[tok * 4 + 0] = l0; out[tok * 4 + 1] = l1;
  out[tok * 4 + 2] = l2; out[tok * 4 + 3] = l3;
  float q0 = 1.f / (1.f + expf(-l0));
  float q1 = 1.f / (1.f + expf(-l1));
  float q2 = 1.f / (1.f + expf(-l2));
  float q3 = 1.f / (1.f + expf(-l3));
  const float eps = 1e-8f;
  float p0 = fmaxf(1.f - q0, eps);
  float p1 = fmaxf(q0 - q1, eps);
  float p2 = fmaxf(q1 - q2, eps);
  float p3 = fmaxf(q2 - q3, eps);
  float p4 = fmaxf(q3, eps);
  float s = p0 + p1 + p2 + p3 + p4;
  float inv = 1.f / fmaxf(s, eps);
  float* pr = out + (size_t)Bn * 4 + (size_t)tok * 5;
  pr[0] = p0 * inv; pr[1] = p1 * inv; pr[2] = p2 * inv;
  pr[3] = p3 * inv; pr[4] = p4 * inv;
}

// ---------- launch ----------
extern "C" void kernel_launch(void* const* d_in, const int* in_sizes, int n_in,
                              void* d_out, int out_size, void* d_ws, size_t ws_size,
                              hipStream_t stream) {
  const float* x  = (const float*)d_in[0];
  const int* sidx = (const int*)d_in[1];
  const float* W1 = (const float*)d_in[2];
  const float* b1 = (const float*)d_in[3];
  const float* W2 = (const float*)d_in[4];
  const float* b2 = (const float*)d_in[5];
  float* out = (float*)d_out;

  uint8_t* w = (uint8_t*)d_ws;
  int* off  = (int*)(w + 64);     // 9 ints
  int* perm = (int*)(w + 512);    // 9216 ints
  u16* xbT     = (u16*)(w + 40960);                        // 18,874,368 B
  u16* w1tT    = (u16*)(w + 40960 + 18874368);             // 16,777,216 B
  float* parts = (float*)(w + 40960 + 18874368 + 16777216);// 2,359,296 B

  prep_r<<<2049, 256, 0, stream>>>(sidx, W1, w1tT, off, perm);
  pack_x<<<PERM_N / 2, 256, 0, stream>>>(x, perm, xbT);
  gemm_k<<<dim3(Hn / 128, MTILES), 256, 0, stream>>>(xbT, w1tT, b1, W2, off, parts);
  probs_k<<<(PERM_N + 255) / 256, 256, 0, stream>>>(parts, perm, off, sidx, b2, out);
}